// Round 11
// baseline (142.044 us; speedup 1.0000x reference)
//
#include <hip/hip_runtime.h>

typedef unsigned short u16;
typedef unsigned char u8;
typedef __attribute__((ext_vector_type(8))) short short8;
typedef __attribute__((ext_vector_type(4))) short short4v;
typedef __attribute__((ext_vector_type(4))) float f32x4;

#define GLD16(g, l) __builtin_amdgcn_global_load_lds( \
    (const __attribute__((address_space(1))) void*)(g), \
    (__attribute__((address_space(3))) void*)(l), 16, 0, 0)

__device__ __forceinline__ float bf2f(u16 u){
  union { unsigned int i; float f; } v; v.i = ((unsigned int)u) << 16; return v.f;
}
__device__ __forceinline__ u16 f2bf(float f){
  union { float f; unsigned int i; } v; v.f = f;
  unsigned int u = v.i;
  unsigned int r = (u + 0x7FFFu + ((u >> 16) & 1u)) >> 16;
  return (u16)r;
}

__device__ __forceinline__ f32x4 mfma16(short4v a, short4v b, f32x4 c){
#if __has_builtin(__builtin_amdgcn_mfma_f32_16x16x16bf16_1k)
  return __builtin_amdgcn_mfma_f32_16x16x16bf16_1k(a, b, c, 0, 0, 0);
#else
  asm volatile("s_nop 1\n\tv_mfma_f32_16x16x16_bf16 %0, %1, %2, %0" : "+v"(c) : "v"(a), "v"(b));
  return c;
#endif
}

// ---------------- fused prep: x->bf16 | Wqkv^T | Wproj^T | rel->u8 ----------------
__global__ __launch_bounds__(256) void prep_k(const float* __restrict__ x, u16* __restrict__ xb,
                                              const float* __restrict__ Wqkv, u16* __restrict__ wqkvT,
                                              const float* __restrict__ Wproj, u16* __restrict__ wprojT,
                                              const int* __restrict__ rel, u8* __restrict__ rel8){
  const int bid = blockIdx.x, t = threadIdx.x;
  if (bid < 4096){
    int i = bid * 256 + t;
    float4 v = ((const float4*)x)[i];
    unsigned long long pk = (unsigned long long)f2bf(v.x)
      | ((unsigned long long)f2bf(v.y) << 16)
      | ((unsigned long long)f2bf(v.z) << 32)
      | ((unsigned long long)f2bf(v.w) << 48);
    ((unsigned long long*)xb)[i] = pk;
  } else if (bid < 8192){
    const float* W; u16* Wt; int K, N, blk, nbx;
    if (bid < 7168){ W = Wqkv; Wt = wqkvT; K = 1024; N = 3072; blk = bid - 4096; nbx = 96; }
    else           { W = Wproj; Wt = wprojT; K = 1024; N = 1024; blk = bid - 7168; nbx = 32; }
    __shared__ float tl[32][33];
    int n0 = (blk % nbx) * 32, k0 = (blk / nbx) * 32;
    int tx = t & 31, ty = t >> 5;
    for (int i = ty; i < 32; i += 8)
      tl[i][tx] = W[(size_t)(k0 + i) * N + n0 + tx];
    __syncthreads();
    for (int i = ty; i < 32; i += 8)
      Wt[(size_t)(n0 + i) * K + k0 + tx] = f2bf(tl[tx][i]);
  } else {
    int i = (bid - 8192) * 256 + t;
    int4 v = ((const int4*)rel)[i];
    unsigned int pk = (unsigned int)(v.x & 255) | ((unsigned int)(v.y & 255) << 8)
      | ((unsigned int)(v.z & 255) << 16) | ((unsigned int)(v.w & 255) << 24);
    ((unsigned int*)rel8)[i] = pk;
  }
}

// ---------------- QKV GEMM: 128x128 tile, BK=32, 3-buffer counted-vmcnt pipeline ----------------
__global__ __launch_bounds__(256) void gemm_qkv_k(const u16* __restrict__ A, const u16* __restrict__ Bt,
                                                  const float* __restrict__ bias,
                                                  u16* __restrict__ oq, u16* __restrict__ okk, u16* __restrict__ vt){
  __shared__ u16 la[3][128 * 32];   // 3 x 8 KB
  __shared__ u16 lb[3][128 * 32];   // 3 x 8 KB
  const int K = 1024;
  const int t = threadIdx.x, w = t >> 6, lane = t & 63;
  const int l15 = lane & 15, l4 = lane >> 4;
  const int m0 = blockIdx.y * 128, n0 = blockIdx.x * 128;
  const int wr = w >> 1, wc = w & 1;
  f32x4 acc[4][4] = {};
  const u16* Abase = A + (size_t)m0 * K;
  const u16* Bbase = Bt + (size_t)n0 * K;

  const int srow0 = t >> 2, srow1 = 64 + (t >> 2);
  const int cg = t & 3;
  const int sc0 = cg ^ (srow0 & 3), sc1 = cg ^ (srow1 & 3);
  const int wbase0 = (w * 64) * 8, wbase1 = (256 + w * 64) * 8;

#define QSTAGE(kt, buf) do {                                                        \
    GLD16(Abase + (size_t)srow0 * K + (kt) * 32 + sc0 * 8, &la[buf][wbase0]);       \
    GLD16(Abase + (size_t)srow1 * K + (kt) * 32 + sc1 * 8, &la[buf][wbase1]);       \
    GLD16(Bbase + (size_t)srow0 * K + (kt) * 32 + sc0 * 8, &lb[buf][wbase0]);       \
    GLD16(Bbase + (size_t)srow1 * K + (kt) * 32 + sc1 * 8, &lb[buf][wbase1]);       \
  } while (0)

  QSTAGE(0, 0);
  QSTAGE(1, 1);
  for (int ki = 0; ki < 32; ++ki){
    __builtin_amdgcn_sched_barrier(0);
    if (ki < 31) asm volatile("s_waitcnt vmcnt(4)" ::: "memory");
    else         asm volatile("s_waitcnt vmcnt(0)" ::: "memory");
    __builtin_amdgcn_s_barrier();
    __builtin_amdgcn_sched_barrier(0);
    if (ki + 2 < 32) QSTAGE(ki + 2, (ki + 2) % 3);
    const int cb = ki % 3;
    short8 af[4], bfr[4];
#pragma unroll
    for (int mi = 0; mi < 4; ++mi){
      int row = wr * 64 + mi * 16 + l15;
      af[mi] = *(const short8*)&la[cb][row * 32 + ((l4 ^ (row & 3)) * 8)];
    }
#pragma unroll
    for (int ni = 0; ni < 4; ++ni){
      int row = wc * 64 + ni * 16 + l15;
      bfr[ni] = *(const short8*)&lb[cb][row * 32 + ((l4 ^ (row & 3)) * 8)];
    }
    __builtin_amdgcn_s_setprio(1);
#pragma unroll
    for (int mi = 0; mi < 4; ++mi)
#pragma unroll
      for (int ni = 0; ni < 4; ++ni)
        acc[mi][ni] = __builtin_amdgcn_mfma_f32_16x16x32_bf16(af[mi], bfr[ni], acc[mi][ni], 0, 0, 0);
    __builtin_amdgcn_s_setprio(0);
  }
#undef QSTAGE

#pragma unroll
  for (int mi = 0; mi < 4; ++mi){
    const int m_base = m0 + wr * 64 + mi * 16 + l4 * 4;
    const int bsel = m_base >> 11, s0q = m_base & 2047;
#pragma unroll
    for (int ni = 0; ni < 4; ++ni){
      int n = n0 + wc * 64 + ni * 16 + l15;
      float vb = bias[n];
      int tt = n >> 10, rr = n & 1023, head = rr >> 6, dd = rr & 63;
      if (tt == 2){
        int c = s0q >> 6, w6 = s0q & 63;
        int pj0 = (((w6 >> 2) & 3) << 4) | (((w6 >> 4) & 3) << 2);
        u16 o4[4];
#pragma unroll
        for (int r = 0; r < 4; ++r) o4[r] = f2bf(acc[mi][ni][r] + vb);
        *(uint2*)(vt + ((size_t)(bsel * 16 + head) * 64 + dd) * 2048 + c * 64 + pj0) = *(const uint2*)o4;
      } else {
        u16* dst = (tt == 0) ? oq : okk;
#pragma unroll
        for (int r = 0; r < 4; ++r)
          dst[(((size_t)(bsel * 16 + head)) * 2048 + s0q + r) * 64 + dd] = f2bf(acc[mi][ni][r] + vb);
      }
    }
  }
}

// ---------------- proj GEMM: 128x64 tile, BK=32, 3-buffer counted-vmcnt, fp32 out ----------------
__global__ __launch_bounds__(256) void gemm_proj_k(const u16* __restrict__ A, const u16* __restrict__ Bt,
                                                   const float* __restrict__ bias, float* __restrict__ of){
  __shared__ u16 la[3][128 * 32];   // 3 x 8 KB
  __shared__ u16 lb[3][64 * 32];    // 3 x 4 KB
  const int K = 1024, N = 1024;
  const int t = threadIdx.x, w = t >> 6, lane = t & 63;
  const int l15 = lane & 15, l4 = lane >> 4;
  const int m0 = blockIdx.y * 128, n0 = blockIdx.x * 64;
  const int wr = w >> 1, wc = w & 1;
  f32x4 acc[4][2] = {};
  const u16* Abase = A + (size_t)m0 * K;
  const u16* Bbase = Bt + (size_t)n0 * K;

  const int srow0 = t >> 2, srow1 = 64 + (t >> 2);
  const int cg = t & 3;
  const int sc0 = cg ^ (srow0 & 3), sc1 = cg ^ (srow1 & 3);
  const int wbase0 = (w * 64) * 8, wbase1 = (256 + w * 64) * 8;

#define PSTAGE(kt, buf) do {                                                        \
    GLD16(Abase + (size_t)srow0 * K + (kt) * 32 + sc0 * 8, &la[buf][wbase0]);       \
    GLD16(Abase + (size_t)srow1 * K + (kt) * 32 + sc1 * 8, &la[buf][wbase1]);       \
    GLD16(Bbase + (size_t)srow0 * K + (kt) * 32 + sc0 * 8, &lb[buf][wbase0]);       \
  } while (0)

  PSTAGE(0, 0);
  PSTAGE(1, 1);
  for (int ki = 0; ki < 32; ++ki){
    __builtin_amdgcn_sched_barrier(0);
    if (ki < 31) asm volatile("s_waitcnt vmcnt(3)" ::: "memory");
    else         asm volatile("s_waitcnt vmcnt(0)" ::: "memory");
    __builtin_amdgcn_s_barrier();
    __builtin_amdgcn_sched_barrier(0);
    if (ki + 2 < 32) PSTAGE(ki + 2, (ki + 2) % 3);
    const int cb = ki % 3;
    short8 af[4], bfr[2];
#pragma unroll
    for (int mi = 0; mi < 4; ++mi){
      int row = wr * 64 + mi * 16 + l15;
      af[mi] = *(const short8*)&la[cb][row * 32 + ((l4 ^ (row & 3)) * 8)];
    }
#pragma unroll
    for (int ni = 0; ni < 2; ++ni){
      int row = wc * 32 + ni * 16 + l15;
      bfr[ni] = *(const short8*)&lb[cb][row * 32 + ((l4 ^ (row & 3)) * 8)];
    }
    __builtin_amdgcn_s_setprio(1);
#pragma unroll
    for (int mi = 0; mi < 4; ++mi)
#pragma unroll
      for (int ni = 0; ni < 2; ++ni)
        acc[mi][ni] = __builtin_amdgcn_mfma_f32_16x16x32_bf16(af[mi], bfr[ni], acc[mi][ni], 0, 0, 0);
    __builtin_amdgcn_s_setprio(0);
  }
#undef PSTAGE

#pragma unroll
  for (int mi = 0; mi < 4; ++mi){
#pragma unroll
    for (int ni = 0; ni < 2; ++ni){
#pragma unroll
      for (int r = 0; r < 4; ++r){
        int m = m0 + wr * 64 + mi * 16 + l4 * 4 + r;
        int n = n0 + wc * 32 + ni * 16 + l15;
        of[(size_t)m * N + n] = acc[mi][ni][r] + bias[n];
      }
    }
  }
}

// ---------------- V chunk sums from vt (perm-invariant) + suffix scan ----------------
__global__ __launch_bounds__(256) void vsuf2_k(const u16* __restrict__ vt, float* __restrict__ vsuf){
  __shared__ float part[32][64];
  const int bh = blockIdx.x;
  const int d = threadIdx.x & 63, qtr = threadIdx.x >> 6;
  const u16* row = vt + ((size_t)bh * 64 + d) * 2048;
  for (int c = qtr * 8; c < qtr * 8 + 8; ++c){
    float s = 0.f;
#pragma unroll
    for (int jv = 0; jv < 8; ++jv){
      short8 v = *(const short8*)(row + c * 64 + jv * 8);
#pragma unroll
      for (int e = 0; e < 8; ++e) s += bf2f((u16)v[e]);
    }
    part[c][d] = s;
  }
  __syncthreads();
  if (threadIdx.x < 64){
    float run = 0.f;
    vsuf[((size_t)bh * 33 + 32) * 64 + d] = 0.f;
    for (int c = 31; c >= 0; --c){
      run += part[c][d];
      vsuf[((size_t)bh * 33 + c) * 64 + d] = run;
    }
  }
}

// ---------------- fused rel-bias causal attention (swapped-operand, cross-block split) ----------------
// remb gather via ds_bpermute (crossbar, conflict-free) against per-lane register.
template<int U8, int SPLIT>
__global__ __launch_bounds__(256, 4) void attn_k(const u16* __restrict__ qb, const u16* __restrict__ kb,
                                                 const u16* __restrict__ vt, const float* __restrict__ vsuf,
                                                 const void* __restrict__ relp, const float* __restrict__ rel_emb,
                                                 u16* __restrict__ ab, float* __restrict__ pacc,
                                                 float* __restrict__ prsum){
  __shared__ u16 Kt[2][64 * 64];
  __shared__ u16 Vt[2][64 * 64];
  int p, hf, bh;
  if (SPLIT){
    const int lid = blockIdx.x;
    const int bhgrp = lid & 7, within = (lid >> 3) & 3, pf = lid >> 5;
    bh = bhgrp * 4 + within;
    p = pf >> 1; hf = pf & 1;
  } else {
    p = blockIdx.x; hf = 0; bh = blockIdx.y;
  }
  const int b = bh >> 4, h = bh & 15;
  const int TA = p, TB = 31 - p;
  const int q0A = TA * 64, q0B = TB * 64;
  const int tid = threadIdx.x, w = tid >> 6, lane = tid & 63;
  const int l15 = lane & 15, l4 = lane >> 4;
  const int remb_bits = __float_as_int(rel_emb[lane * 16 + h] * (0.125f * 1.44269504088896f));
  const u16* kbh = kb + ((size_t)bh * 2048) * 64;
  const u16* vbh = vt + ((size_t)bh * 64) * 2048;
  const u16* qA = qb + (((size_t)bh * 2048) + q0A + w * 16 + l15) * 64 + l4 * 8;
  const u16* qB = qb + (((size_t)bh * 2048) + q0B + w * 16 + l15) * 64 + l4 * 8;
  const short8 aqA0 = *(const short8*)qA, aqA1 = *(const short8*)(qA + 32);
  const short8 aqB0 = *(const short8*)qB, aqB1 = *(const short8*)(qB + 32);
  const u8*  r8A  = (const u8*)relp + ((size_t)b * 2048 + q0A + w * 16 + l15) * 2048;
  const u8*  r8B  = (const u8*)relp + ((size_t)b * 2048 + q0B + w * 16 + l15) * 2048;
  const int* r32A = (const int*)relp + ((size_t)b * 2048 + q0A + w * 16 + l15) * 2048;
  const int* r32B = (const int*)relp + ((size_t)b * 2048 + q0B + w * 16 + l15) * 2048;

  const int srow0 = (tid >> 3), srow1 = 32 + (tid >> 3);
  const int scs = tid & 7;
  const int sc0 = scs ^ (srow0 & 7), sc1 = scs ^ (srow1 & 7);
  const int sldsoff = (w * 64) * 8;

#define STAGE(ktile, buf) do {                                                       \
    GLD16(kbh + (size_t)((ktile) * 64 + srow0) * 64 + sc0 * 8, &Kt[buf][sldsoff]);   \
    GLD16(kbh + (size_t)((ktile) * 64 + srow1) * 64 + sc1 * 8, &Kt[buf][2048 + sldsoff]); \
    GLD16(vbh + (size_t)srow0 * 2048 + (ktile) * 64 + sc0 * 8, &Vt[buf][sldsoff]);   \
    GLD16(vbh + (size_t)srow1 * 2048 + (ktile) * 64 + sc1 * 8, &Vt[buf][2048 + sldsoff]); \
  } while (0)

  f32x4 acc[4] = {};
  float rsum = 0.f;
  unsigned int relc[4], reln[4];

  auto relload = [&](bool isA, int kt, unsigned int* dst){
    int off = kt * 64 + 4 * l4;
    if (U8){
      const u8* pp = isA ? r8A : r8B;
#pragma unroll
      for (int t = 0; t < 4; ++t) dst[t] = *(const unsigned int*)(pp + off + 16 * t);
    } else {
      const int* pp = isA ? r32A : r32B;
#pragma unroll
      for (int t = 0; t < 4; ++t){
        int4 v4 = *(const int4*)(pp + off + 16 * t);
        dst[t] = (unsigned int)(v4.x & 255) | ((unsigned int)(v4.y & 255) << 8)
               | ((unsigned int)(v4.z & 255) << 16) | ((unsigned int)(v4.w & 255) << 24);
      }
    }
  };

  auto writeout = [&](int Td, int q0){
    asm volatile("s_nop 7\n\ts_nop 7" :::);
    float s = rsum;
    s += __shfl_xor(s, 16);
    s += __shfl_xor(s, 32);
    float invZ = 1.f / (s + (float)(2048 - (Td + 1) * 64));
    int qg = q0 + w * 16 + l15;
    const float* sufp = vsuf + ((size_t)bh * 33 + Td + 1) * 64;
#pragma unroll
    for (int ni = 0; ni < 4; ++ni){
      float4 sv = *(const float4*)(sufp + ni * 16 + 4 * l4);
      unsigned int lo2 = (unsigned int)f2bf((acc[ni][0] + sv.x) * invZ)
                       | ((unsigned int)f2bf((acc[ni][1] + sv.y) * invZ) << 16);
      unsigned int hi2 = (unsigned int)f2bf((acc[ni][2] + sv.z) * invZ)
                       | ((unsigned int)f2bf((acc[ni][3] + sv.w) * invZ) << 16);
      uint2 o; o.x = lo2; o.y = hi2;
      *(uint2*)(ab + ((size_t)b * 2048 + qg) * 1024 + h * 64 + ni * 16 + 4 * l4) = o;
    }
  };

  const int lo = (SPLIT && hf) ? 17 : 0;
  const int hi = (SPLIT && !hf) ? 17 : 33;

  {
    bool isA0 = (lo <= TA);
    int kt0 = isA0 ? lo : lo - TA - 1;
    STAGE(kt0, 0);
    relload(isA0, kt0, relc);
  }
  __syncthreads();

  for (int it = lo; it < hi; ++it){
    const bool isA = (it <= TA);
    const int kt = isA ? it : (it - TA - 1);
    const int cur = (it - lo) & 1;

    if (it + 1 < hi){
      const bool nA = (it + 1 <= TA);
      const int nkt = nA ? (it + 1) : (it - TA);
      STAGE(nkt, cur ^ 1);
      relload(nA, nkt, reln);
    }

    const short8 a0 = isA ? aqA0 : aqB0;
    const short8 a1 = isA ? aqA1 : aqB1;
    const bool diag = (kt == (isA ? TA : TB));

    short4v pk[4];
    __builtin_amdgcn_s_setprio(1);
#pragma unroll
    for (int t = 0; t < 4; ++t){
      const int krow = 16 * t + l15;
      const u16* kbase = &Kt[cur][krow * 64];
      short8 bk0 = *(const short8*)&kbase[((l4)     ^ (krow & 7)) * 8];
      short8 bk1 = *(const short8*)&kbase[((4 + l4) ^ (krow & 7)) * 8];
      f32x4 sf = {0.f, 0.f, 0.f, 0.f};
      sf = __builtin_amdgcn_mfma_f32_16x16x32_bf16(bk0, a0, sf, 0, 0, 0);
      sf = __builtin_amdgcn_mfma_f32_16x16x32_bf16(bk1, a1, sf, 0, 0, 0);
      unsigned int rw = relc[t];
      const int kk = 16 * t + 4 * l4;
      float prv[4];
#pragma unroll
      for (int r = 0; r < 4; ++r){
        int idx4 = (int)((rw >> (8 * r)) & 255u) << 2;
        float rwf = __int_as_float(__builtin_amdgcn_ds_bpermute(idx4, remb_bits));
        float sc = sf[r] * rwf;
        if (diag) sc = (kk + r <= w * 16 + l15) ? sc : 0.f;
        float pv = __builtin_amdgcn_exp2f(sc);
        rsum += pv;
        prv[r] = pv;
      }
      union { unsigned int u[2]; short4v s; } pu;
      asm("v_cvt_pk_bf16_f32 %0, %1, %2" : "=v"(pu.u[0]) : "v"(prv[0]), "v"(prv[1]));
      asm("v_cvt_pk_bf16_f32 %0, %1, %2" : "=v"(pu.u[1]) : "v"(prv[2]), "v"(prv[3]));
      pk[t] = pu.s;
    }
    asm volatile("s_nop 2" :::);
#pragma unroll
    for (int ni = 0; ni < 4; ++ni){
      const int drow = ni * 16 + l15;
      const u16* vbase = &Vt[cur][drow * 64];
      short8 vv0 = *(const short8*)&vbase[(((2 * l4)     ^ (drow & 7))) * 8];
      short8 vv1 = *(const short8*)&vbase[(((2 * l4 + 1) ^ (drow & 7))) * 8];
      short4v va0 = {vv0[0], vv0[1], vv0[2], vv0[3]};
      short4v va1 = {vv0[4], vv0[5], vv0[6], vv0[7]};
      short4v va2 = {vv1[0], vv1[1], vv1[2], vv1[3]};
      short4v va3 = {vv1[4], vv1[5], vv1[6], vv1[7]};
      acc[ni] = mfma16(va0, pk[0], acc[ni]);
      acc[ni] = mfma16(va1, pk[1], acc[ni]);
      acc[ni] = mfma16(va2, pk[2], acc[ni]);
      acc[ni] = mfma16(va3, pk[3], acc[ni]);
    }
    __builtin_amdgcn_s_setprio(0);

    if (it == TA){   // A complete (only reachable when hf==0)
      writeout(TA, q0A);
#pragma unroll
      for (int ni = 0; ni < 4; ++ni) acc[ni] = f32x4{0.f, 0.f, 0.f, 0.f};
      rsum = 0.f;
    }
    if (it + 1 < hi){
#pragma unroll
      for (int t = 0; t < 4; ++t) relc[t] = reln[t];
    }
    __syncthreads();
  }
#undef STAGE

  if (SPLIT){
    asm volatile("s_nop 7\n\ts_nop 7" :::);
    float s = rsum;
    s += __shfl_xor(s, 16);
    s += __shfl_xor(s, 32);
    const size_t slot = (((size_t)bh * 16 + p) * 2 + hf);
    float* pslot = pacc + slot * 4096;
#pragma unroll
    for (int ni = 0; ni < 4; ++ni)
      *(f32x4*)(pslot + (w * 16 + l15) * 64 + ni * 16 + 4 * l4) = acc[ni];
    if (l4 == 0) prsum[slot * 64 + w * 16 + l15] = s;
  } else {
    writeout(TB, q0B);
  }
}

// ---------------- combine B partials + suffix + normalize + store ----------------
__global__ __launch_bounds__(256) void attn_fin_k(const float* __restrict__ pacc,
                                                  const float* __restrict__ prsum,
                                                  const float* __restrict__ vsuf,
                                                  u16* __restrict__ ab){
  const int p = blockIdx.x, bh = blockIdx.y;
  const int b = bh >> 4, h = bh & 15;
  const int TB = 31 - p, q0 = TB * 64;
  const int r = threadIdx.x >> 2, cg = threadIdx.x & 3;
  const size_t slot = ((size_t)bh * 16 + p) * 2;
  const size_t base = slot * 4096 + r * 64 + cg * 16;
  float rs = prsum[slot * 64 + r] + prsum[(slot + 1) * 64 + r];
  float invZ = 1.f / (rs + (float)(2048 - (TB + 1) * 64));
  const float* sufp = vsuf + ((size_t)bh * 33 + TB + 1) * 64 + cg * 16;
  u16 o[16];
#pragma unroll
  for (int j = 0; j < 4; ++j){
    f32x4 a0 = *(const f32x4*)(pacc + base + j * 4);
    f32x4 a1 = *(const f32x4*)(pacc + base + 4096 + j * 4);
    f32x4 sv = *(const f32x4*)(sufp + j * 4);
#pragma unroll
    for (int e = 0; e < 4; ++e) o[j * 4 + e] = f2bf((a0[e] + a1[e] + sv[e]) * invZ);
  }
  u16* dst = ab + ((size_t)b * 2048 + q0 + r) * 1024 + h * 64 + cg * 16;
  *(uint4*)dst = *(const uint4*)&o[0];
  *(uint4*)(dst + 8) = *(const uint4*)&o[8];
}

// ---------------- launch ----------------
extern "C" void kernel_launch(void* const* d_in, const int* in_sizes, int n_in,
                              void* d_out, int out_size, void* d_ws, size_t ws_size,
                              hipStream_t stream){
  const float* x       = (const float*)d_in[0];
  const float* Wqkv    = (const float*)d_in[1];
  const float* bqkv    = (const float*)d_in[2];
  const float* Wproj   = (const float*)d_in[3];
  const float* bproj   = (const float*)d_in[4];
  const float* rel_emb = (const float*)d_in[5];
  const int*   rel     = (const int*)d_in[6];
  float* out = (float*)d_out;

  char* ws = (char*)d_ws;
  u16* xb     = (u16*)(ws);                      // 8 MB (x bf16; later attn output)
  u16* wqkvT  = (u16*)(ws + (8ull  << 20));      // 6 MB
  u16* wprojT = (u16*)(ws + (14ull << 20));      // 2 MB
  u16* qb     = (u16*)(ws + (16ull << 20));      // 8 MB
  u16* kb     = (u16*)(ws + (24ull << 20));      // 8 MB
  u16* vtb    = (u16*)(ws + (40ull << 20));      // 8 MB (V, transposed+permuted)
  float* vsuf = (float*)(ws + (48ull << 20));                   // 270 KB
  float* pacc = (float*)(ws + (49ull << 20));    // 16 MB (B partials, SPLIT only)
  float* prsum= (float*)(ws + (65ull << 20) + (512ull << 10));  // 256 KB
  u8*   rel8  = (u8*)(ws + (66ull << 20));       // 8.4 MB
  const bool useSplit = ws_size >= (67ull << 20);
  const bool useU8    = ws_size >= (75ull << 20);

  prep_k<<<useU8 ? 16384 : 8192, 256, 0, stream>>>(x, xb, Wqkv, wqkvT, Wproj, wprojT, rel, rel8);
  gemm_qkv_k<<<dim3(24, 32), 256, 0, stream>>>(xb, wqkvT, bqkv, qb, kb, vtb);
  vsuf2_k<<<32, 256, 0, stream>>>(vtb, vsuf);
  if (useU8)
    attn_k<1, 1><<<dim3(1024), 256, 0, stream>>>(qb, kb, vtb, vsuf, rel8, rel_emb, xb, pacc, prsum);
  else if (useSplit)
    attn_k<0, 1><<<dim3(1024), 256, 0, stream>>>(qb, kb, vtb, vsuf, rel, rel_emb, xb, pacc, prsum);
  else
    attn_k<0, 0><<<dim3(16, 32), 256, 0, stream>>>(qb, kb, vtb, vsuf, rel, rel_emb, xb, pacc, prsum);
  if (useSplit || useU8)
    attn_fin_k<<<dim3(16, 32), 256, 0, stream>>>(pacc, prsum, vsuf, xb);
  gemm_proj_k<<<dim3(16, 32), 256, 0, stream>>>(xb, wprojT, bproj, out);
}

// Round 12
// 141.271 us; speedup vs baseline: 1.0055x; 1.0055x over previous
//
#include <hip/hip_runtime.h>

typedef unsigned short u16;
typedef unsigned char u8;
typedef __attribute__((ext_vector_type(8))) short short8;
typedef __attribute__((ext_vector_type(4))) short short4v;
typedef __attribute__((ext_vector_type(4))) float f32x4;

#define GLD16(g, l) __builtin_amdgcn_global_load_lds( \
    (const __attribute__((address_space(1))) void*)(g), \
    (__attribute__((address_space(3))) void*)(l), 16, 0, 0)

__device__ __forceinline__ float bf2f(u16 u){
  union { unsigned int i; float f; } v; v.i = ((unsigned int)u) << 16; return v.f;
}
__device__ __forceinline__ u16 f2bf(float f){
  union { float f; unsigned int i; } v; v.f = f;
  unsigned int u = v.i;
  unsigned int r = (u + 0x7FFFu + ((u >> 16) & 1u)) >> 16;
  return (u16)r;
}

__device__ __forceinline__ f32x4 mfma16(short4v a, short4v b, f32x4 c){
#if __has_builtin(__builtin_amdgcn_mfma_f32_16x16x16bf16_1k)
  return __builtin_amdgcn_mfma_f32_16x16x16bf16_1k(a, b, c, 0, 0, 0);
#else
  asm volatile("s_nop 1\n\tv_mfma_f32_16x16x16_bf16 %0, %1, %2, %0" : "+v"(c) : "v"(a), "v"(b));
  return c;
#endif
}

// ---------------- fused prep: x->bf16 | Wqkv^T | Wproj^T | rel->u8 ----------------
__global__ __launch_bounds__(256) void prep_k(const float* __restrict__ x, u16* __restrict__ xb,
                                              const float* __restrict__ Wqkv, u16* __restrict__ wqkvT,
                                              const float* __restrict__ Wproj, u16* __restrict__ wprojT,
                                              const int* __restrict__ rel, u8* __restrict__ rel8){
  const int bid = blockIdx.x, t = threadIdx.x;
  if (bid < 4096){
    int i = bid * 256 + t;
    float4 v = ((const float4*)x)[i];
    unsigned long long pk = (unsigned long long)f2bf(v.x)
      | ((unsigned long long)f2bf(v.y) << 16)
      | ((unsigned long long)f2bf(v.z) << 32)
      | ((unsigned long long)f2bf(v.w) << 48);
    ((unsigned long long*)xb)[i] = pk;
  } else if (bid < 8192){
    const float* W; u16* Wt; int K, N, blk, nbx;
    if (bid < 7168){ W = Wqkv; Wt = wqkvT; K = 1024; N = 3072; blk = bid - 4096; nbx = 96; }
    else           { W = Wproj; Wt = wprojT; K = 1024; N = 1024; blk = bid - 7168; nbx = 32; }
    __shared__ float tl[32][33];
    int n0 = (blk % nbx) * 32, k0 = (blk / nbx) * 32;
    int tx = t & 31, ty = t >> 5;
    for (int i = ty; i < 32; i += 8)
      tl[i][tx] = W[(size_t)(k0 + i) * N + n0 + tx];
    __syncthreads();
    for (int i = ty; i < 32; i += 8)
      Wt[(size_t)(n0 + i) * K + k0 + tx] = f2bf(tl[tx][i]);
  } else {
    int i = (bid - 8192) * 256 + t;
    int4 v = ((const int4*)rel)[i];
    unsigned int pk = (unsigned int)(v.x & 255) | ((unsigned int)(v.y & 255) << 8)
      | ((unsigned int)(v.z & 255) << 16) | ((unsigned int)(v.w & 255) << 24);
    ((unsigned int*)rel8)[i] = pk;
  }
}

// ---------------- QKV GEMM: 128x128 tile, BK=32, 3-buffer counted-vmcnt pipeline ----------------
__global__ __launch_bounds__(256) void gemm_qkv_k(const u16* __restrict__ A, const u16* __restrict__ Bt,
                                                  const float* __restrict__ bias,
                                                  u16* __restrict__ oq, u16* __restrict__ okk, u16* __restrict__ vt){
  __shared__ u16 la[3][128 * 32];   // 3 x 8 KB
  __shared__ u16 lb[3][128 * 32];   // 3 x 8 KB
  const int K = 1024;
  const int t = threadIdx.x, w = t >> 6, lane = t & 63;
  const int l15 = lane & 15, l4 = lane >> 4;
  const int m0 = blockIdx.y * 128, n0 = blockIdx.x * 128;
  const int wr = w >> 1, wc = w & 1;
  f32x4 acc[4][4] = {};
  const u16* Abase = A + (size_t)m0 * K;
  const u16* Bbase = Bt + (size_t)n0 * K;

  const int srow0 = t >> 2, srow1 = 64 + (t >> 2);
  const int cg = t & 3;
  const int sc0 = cg ^ (srow0 & 3), sc1 = cg ^ (srow1 & 3);
  const int wbase0 = (w * 64) * 8, wbase1 = (256 + w * 64) * 8;

#define QSTAGE(kt, buf) do {                                                        \
    GLD16(Abase + (size_t)srow0 * K + (kt) * 32 + sc0 * 8, &la[buf][wbase0]);       \
    GLD16(Abase + (size_t)srow1 * K + (kt) * 32 + sc1 * 8, &la[buf][wbase1]);       \
    GLD16(Bbase + (size_t)srow0 * K + (kt) * 32 + sc0 * 8, &lb[buf][wbase0]);       \
    GLD16(Bbase + (size_t)srow1 * K + (kt) * 32 + sc1 * 8, &lb[buf][wbase1]);       \
  } while (0)

  QSTAGE(0, 0);
  QSTAGE(1, 1);
  for (int ki = 0; ki < 32; ++ki){
    __builtin_amdgcn_sched_barrier(0);
    if (ki < 31) asm volatile("s_waitcnt vmcnt(4)" ::: "memory");
    else         asm volatile("s_waitcnt vmcnt(0)" ::: "memory");
    __builtin_amdgcn_s_barrier();
    __builtin_amdgcn_sched_barrier(0);
    if (ki + 2 < 32) QSTAGE(ki + 2, (ki + 2) % 3);
    const int cb = ki % 3;
    short8 af[4], bfr[4];
#pragma unroll
    for (int mi = 0; mi < 4; ++mi){
      int row = wr * 64 + mi * 16 + l15;
      af[mi] = *(const short8*)&la[cb][row * 32 + ((l4 ^ (row & 3)) * 8)];
    }
#pragma unroll
    for (int ni = 0; ni < 4; ++ni){
      int row = wc * 64 + ni * 16 + l15;
      bfr[ni] = *(const short8*)&lb[cb][row * 32 + ((l4 ^ (row & 3)) * 8)];
    }
    __builtin_amdgcn_s_setprio(1);
#pragma unroll
    for (int mi = 0; mi < 4; ++mi)
#pragma unroll
      for (int ni = 0; ni < 4; ++ni)
        acc[mi][ni] = __builtin_amdgcn_mfma_f32_16x16x32_bf16(af[mi], bfr[ni], acc[mi][ni], 0, 0, 0);
    __builtin_amdgcn_s_setprio(0);
  }
#undef QSTAGE

#pragma unroll
  for (int mi = 0; mi < 4; ++mi){
    const int m_base = m0 + wr * 64 + mi * 16 + l4 * 4;
    const int bsel = m_base >> 11, s0q = m_base & 2047;
#pragma unroll
    for (int ni = 0; ni < 4; ++ni){
      int n = n0 + wc * 64 + ni * 16 + l15;
      float vb = bias[n];
      int tt = n >> 10, rr = n & 1023, head = rr >> 6, dd = rr & 63;
      if (tt == 2){
        int c = s0q >> 6, w6 = s0q & 63;
        int pj0 = (((w6 >> 2) & 3) << 4) | (((w6 >> 4) & 3) << 2);
        u16 o4[4];
#pragma unroll
        for (int r = 0; r < 4; ++r) o4[r] = f2bf(acc[mi][ni][r] + vb);
        *(uint2*)(vt + ((size_t)(bsel * 16 + head) * 64 + dd) * 2048 + c * 64 + pj0) = *(const uint2*)o4;
      } else {
        u16* dst = (tt == 0) ? oq : okk;
#pragma unroll
        for (int r = 0; r < 4; ++r)
          dst[(((size_t)(bsel * 16 + head)) * 2048 + s0q + r) * 64 + dd] = f2bf(acc[mi][ni][r] + vb);
      }
    }
  }
}

// ---------------- proj GEMM (B^T input), BK=64, XOR-swizzled LDS, fp32 out ----------------
template<int BN>
__global__ __launch_bounds__(256) void gemm_bt_k(const u16* __restrict__ A, const u16* __restrict__ Bt,
                                                 const float* __restrict__ bias, float* __restrict__ of,
                                                 int M, int N, int K){
  __shared__ u16 la[128 * 64];
  __shared__ u16 lb[BN * 64];
  const int t = threadIdx.x, w = t >> 6, lane = t & 63;
  const int l15 = lane & 15, l4 = lane >> 4;
  const int m0 = blockIdx.y * 128, n0 = blockIdx.x * BN;
  const int wr = w >> 1, wc = w & 1;
  constexpr int NI = BN / 32;
  f32x4 acc[4][NI] = {};
  const u16* Abase = A + (size_t)m0 * K;
  const u16* Bbase = Bt + (size_t)n0 * K;
  for (int kt = 0; kt < K; kt += 64){
    __syncthreads();
#pragma unroll
    for (int i = 0; i < 4; ++i){
      int chunk = i * 256 + t;
      int row = chunk >> 3, cs = chunk & 7;
      int c = cs ^ (row & 7);
      GLD16(Abase + (size_t)row * K + kt + c * 8, &la[(i * 256 + w * 64) * 8]);
    }
#pragma unroll
    for (int i = 0; i < BN / 32; ++i){
      int chunk = i * 256 + t;
      int row = chunk >> 3, cs = chunk & 7;
      int c = cs ^ (row & 7);
      GLD16(Bbase + (size_t)row * K + kt + c * 8, &lb[(i * 256 + w * 64) * 8]);
    }
    asm volatile("s_waitcnt vmcnt(0)" ::: "memory");
    __syncthreads();
    short8 af[4][2], bfr[NI][2];
#pragma unroll
    for (int mi = 0; mi < 4; ++mi){
      int row = wr * 64 + mi * 16 + l15;
#pragma unroll
      for (int h = 0; h < 2; ++h)
        af[mi][h] = *(const short8*)&la[row * 64 + (((h * 4 + l4) ^ (row & 7)) * 8)];
    }
#pragma unroll
    for (int ni = 0; ni < NI; ++ni){
      int row = wc * (BN / 2) + ni * 16 + l15;
#pragma unroll
      for (int h = 0; h < 2; ++h)
        bfr[ni][h] = *(const short8*)&lb[row * 64 + (((h * 4 + l4) ^ (row & 7)) * 8)];
    }
#pragma unroll
    for (int mi = 0; mi < 4; ++mi)
#pragma unroll
      for (int ni = 0; ni < NI; ++ni){
        acc[mi][ni] = __builtin_amdgcn_mfma_f32_16x16x32_bf16(af[mi][0], bfr[ni][0], acc[mi][ni], 0, 0, 0);
        acc[mi][ni] = __builtin_amdgcn_mfma_f32_16x16x32_bf16(af[mi][1], bfr[ni][1], acc[mi][ni], 0, 0, 0);
      }
  }
#pragma unroll
  for (int mi = 0; mi < 4; ++mi){
#pragma unroll
    for (int ni = 0; ni < NI; ++ni){
#pragma unroll
      for (int r = 0; r < 4; ++r){
        int m = m0 + wr * 64 + mi * 16 + l4 * 4 + r;
        int n = n0 + wc * (BN / 2) + ni * 16 + l15;
        of[(size_t)m * N + n] = acc[mi][ni][r] + bias[n];
      }
    }
  }
}

// ---------------- V chunk sums from vt (perm-invariant) + suffix scan ----------------
__global__ __launch_bounds__(256) void vsuf2_k(const u16* __restrict__ vt, float* __restrict__ vsuf){
  __shared__ float part[32][64];
  const int bh = blockIdx.x;
  const int d = threadIdx.x & 63, qtr = threadIdx.x >> 6;
  const u16* row = vt + ((size_t)bh * 64 + d) * 2048;
  for (int c = qtr * 8; c < qtr * 8 + 8; ++c){
    float s = 0.f;
#pragma unroll
    for (int jv = 0; jv < 8; ++jv){
      short8 v = *(const short8*)(row + c * 64 + jv * 8);
#pragma unroll
      for (int e = 0; e < 8; ++e) s += bf2f((u16)v[e]);
    }
    part[c][d] = s;
  }
  __syncthreads();
  if (threadIdx.x < 64){
    float run = 0.f;
    vsuf[((size_t)bh * 33 + 32) * 64 + d] = 0.f;
    for (int c = 31; c >= 0; --c){
      run += part[c][d];
      vsuf[((size_t)bh * 33 + c) * 64 + d] = run;
    }
  }
}

// ---------------- fused rel-bias causal attention ----------------
// SPLIT=1: 3-way split-K: grid 1536, lid -> (bhgrp=lid&7, within, pu): bh XCD-grouped;
//   p = pu/3, unit u = pu%3 runs virtual iters [11u, 11u+11) of the pair's 33.
//   Each unit emits bf16 unnormalized partials (+f32 rsum); fin2 combines.
// SPLIT=0: grid (16,32), full 33 iters, direct writes.
template<int U8, int SPLIT>
__global__ __launch_bounds__(256, 4) void attn_k(const u16* __restrict__ qb, const u16* __restrict__ kb,
                                                 const u16* __restrict__ vt, const float* __restrict__ vsuf,
                                                 const void* __restrict__ relp, const float* __restrict__ rel_emb,
                                                 u16* __restrict__ ab, u16* __restrict__ paccb,
                                                 float* __restrict__ prsum){
  __shared__ u16 Kt[2][64 * 64];
  __shared__ u16 Vt[2][64 * 64];
  int p, u_, bh;
  if (SPLIT){
    const int lid = blockIdx.x;
    const int bhgrp = lid & 7, within = (lid >> 3) & 3, pu = lid >> 5;
    bh = bhgrp * 4 + within;
    p = pu / 3; u_ = pu % 3;
  } else {
    p = blockIdx.x; u_ = 0; bh = blockIdx.y;
  }
  const int b = bh >> 4, h = bh & 15;
  const int TA = p, TB = 31 - p;
  const int q0A = TA * 64, q0B = TB * 64;
  const int tid = threadIdx.x, w = tid >> 6, lane = tid & 63;
  const int l15 = lane & 15, l4 = lane >> 4;
  const int remb_bits = __float_as_int(rel_emb[lane * 16 + h] * (0.125f * 1.44269504088896f));
  const u16* kbh = kb + ((size_t)bh * 2048) * 64;
  const u16* vbh = vt + ((size_t)bh * 64) * 2048;
  const u16* qA = qb + (((size_t)bh * 2048) + q0A + w * 16 + l15) * 64 + l4 * 8;
  const u16* qB = qb + (((size_t)bh * 2048) + q0B + w * 16 + l15) * 64 + l4 * 8;
  const short8 aqA0 = *(const short8*)qA, aqA1 = *(const short8*)(qA + 32);
  const short8 aqB0 = *(const short8*)qB, aqB1 = *(const short8*)(qB + 32);
  const u8*  r8A  = (const u8*)relp + ((size_t)b * 2048 + q0A + w * 16 + l15) * 2048;
  const u8*  r8B  = (const u8*)relp + ((size_t)b * 2048 + q0B + w * 16 + l15) * 2048;
  const int* r32A = (const int*)relp + ((size_t)b * 2048 + q0A + w * 16 + l15) * 2048;
  const int* r32B = (const int*)relp + ((size_t)b * 2048 + q0B + w * 16 + l15) * 2048;

  const int srow0 = (tid >> 3), srow1 = 32 + (tid >> 3);
  const int scs = tid & 7;
  const int sc0 = scs ^ (srow0 & 7), sc1 = scs ^ (srow1 & 7);
  const int sldsoff = (w * 64) * 8;

#define STAGE(ktile, buf) do {                                                       \
    GLD16(kbh + (size_t)((ktile) * 64 + srow0) * 64 + sc0 * 8, &Kt[buf][sldsoff]);   \
    GLD16(kbh + (size_t)((ktile) * 64 + srow1) * 64 + sc1 * 8, &Kt[buf][2048 + sldsoff]); \
    GLD16(vbh + (size_t)srow0 * 2048 + (ktile) * 64 + sc0 * 8, &Vt[buf][sldsoff]);   \
    GLD16(vbh + (size_t)srow1 * 2048 + (ktile) * 64 + sc1 * 8, &Vt[buf][2048 + sldsoff]); \
  } while (0)

  f32x4 acc[4] = {};
  float rsum = 0.f;
  unsigned int relc[4], reln[4];

  auto relload = [&](bool isA, int kt, unsigned int* dst){
    int off = kt * 64 + 4 * l4;
    if (U8){
      const u8* pp = isA ? r8A : r8B;
#pragma unroll
      for (int t = 0; t < 4; ++t) dst[t] = *(const unsigned int*)(pp + off + 16 * t);
    } else {
      const int* pp = isA ? r32A : r32B;
#pragma unroll
      for (int t = 0; t < 4; ++t){
        int4 v4 = *(const int4*)(pp + off + 16 * t);
        dst[t] = (unsigned int)(v4.x & 255) | ((unsigned int)(v4.y & 255) << 8)
               | ((unsigned int)(v4.z & 255) << 16) | ((unsigned int)(v4.w & 255) << 24);
      }
    }
  };

  auto writeout = [&](int Td, int q0){   // SPLIT=0 direct path
    asm volatile("s_nop 7\n\ts_nop 7" :::);
    float s = rsum;
    s += __shfl_xor(s, 16);
    s += __shfl_xor(s, 32);
    float invZ = 1.f / (s + (float)(2048 - (Td + 1) * 64));
    int qg = q0 + w * 16 + l15;
    const float* sufp = vsuf + ((size_t)bh * 33 + Td + 1) * 64;
#pragma unroll
    for (int ni = 0; ni < 4; ++ni){
      float4 sv = *(const float4*)(sufp + ni * 16 + 4 * l4);
      unsigned int lo2 = (unsigned int)f2bf((acc[ni][0] + sv.x) * invZ)
                       | ((unsigned int)f2bf((acc[ni][1] + sv.y) * invZ) << 16);
      unsigned int hi2 = (unsigned int)f2bf((acc[ni][2] + sv.z) * invZ)
                       | ((unsigned int)f2bf((acc[ni][3] + sv.w) * invZ) << 16);
      uint2 o; o.x = lo2; o.y = hi2;
      *(uint2*)(ab + ((size_t)b * 2048 + qg) * 1024 + h * 64 + ni * 16 + 4 * l4) = o;
    }
  };

  auto emitP = [&](int t01){   // SPLIT=1 partial emit (bf16 acc + f32 rsum)
    asm volatile("s_nop 7\n\ts_nop 7" :::);
    float s = rsum;
    s += __shfl_xor(s, 16);
    s += __shfl_xor(s, 32);
    const size_t slot = (((size_t)bh * 16 + p) * 3 + u_) * 2 + t01;
    u16* pbase = paccb + slot * 4096 + (size_t)(w * 16 + l15) * 64;
#pragma unroll
    for (int ni = 0; ni < 4; ++ni){
      unsigned int w0, w1;
      asm("v_cvt_pk_bf16_f32 %0, %1, %2" : "=v"(w0) : "v"(acc[ni][0]), "v"(acc[ni][1]));
      asm("v_cvt_pk_bf16_f32 %0, %1, %2" : "=v"(w1) : "v"(acc[ni][2]), "v"(acc[ni][3]));
      uint2 o; o.x = w0; o.y = w1;
      *(uint2*)(pbase + ni * 16 + 4 * l4) = o;
    }
    if (l4 == 0) prsum[slot * 64 + w * 16 + l15] = s;
  };

  const int lo = SPLIT ? 11 * u_ : 0;
  const int hi = SPLIT ? lo + 11 : 33;

  {
    bool isA0 = (lo <= TA);
    int kt0 = isA0 ? lo : lo - TA - 1;
    STAGE(kt0, 0);
    relload(isA0, kt0, relc);
  }
  __syncthreads();

  for (int it = lo; it < hi; ++it){
    const bool isA = (it <= TA);
    const int kt = isA ? it : (it - TA - 1);
    const int cur = (it - lo) & 1;

    if (it + 1 < hi){
      const bool nA = (it + 1 <= TA);
      const int nkt = nA ? (it + 1) : (it - TA);
      STAGE(nkt, cur ^ 1);
      relload(nA, nkt, reln);
    }

    const short8 a0 = isA ? aqA0 : aqB0;
    const short8 a1 = isA ? aqA1 : aqB1;
    const bool diag = (kt == (isA ? TA : TB));

    short4v pk[4];
    __builtin_amdgcn_s_setprio(1);
#pragma unroll
    for (int t = 0; t < 4; ++t){
      const int krow = 16 * t + l15;
      const u16* kbase = &Kt[cur][krow * 64];
      short8 bk0 = *(const short8*)&kbase[((l4)     ^ (krow & 7)) * 8];
      short8 bk1 = *(const short8*)&kbase[((4 + l4) ^ (krow & 7)) * 8];
      f32x4 sf = {0.f, 0.f, 0.f, 0.f};
      sf = __builtin_amdgcn_mfma_f32_16x16x32_bf16(bk0, a0, sf, 0, 0, 0);
      sf = __builtin_amdgcn_mfma_f32_16x16x32_bf16(bk1, a1, sf, 0, 0, 0);
      unsigned int rw = relc[t];
      const int kk = 16 * t + 4 * l4;
      float prv[4];
#pragma unroll
      for (int r = 0; r < 4; ++r){
        int idx4 = (int)((rw >> (8 * r)) & 255u) << 2;
        float rwf = __int_as_float(__builtin_amdgcn_ds_bpermute(idx4, remb_bits));
        float sc = sf[r] * rwf;
        if (diag) sc = (kk + r <= w * 16 + l15) ? sc : 0.f;
        float pv = __builtin_amdgcn_exp2f(sc);
        rsum += pv;
        prv[r] = pv;
      }
      union { unsigned int u[2]; short4v s; } pu2;
      asm("v_cvt_pk_bf16_f32 %0, %1, %2" : "=v"(pu2.u[0]) : "v"(prv[0]), "v"(prv[1]));
      asm("v_cvt_pk_bf16_f32 %0, %1, %2" : "=v"(pu2.u[1]) : "v"(prv[2]), "v"(prv[3]));
      pk[t] = pu2.s;
    }
    asm volatile("s_nop 2" :::);
#pragma unroll
    for (int ni = 0; ni < 4; ++ni){
      const int drow = ni * 16 + l15;
      const u16* vbase = &Vt[cur][drow * 64];
      short8 vv0 = *(const short8*)&vbase[(((2 * l4)     ^ (drow & 7))) * 8];
      short8 vv1 = *(const short8*)&vbase[(((2 * l4 + 1) ^ (drow & 7))) * 8];
      short4v va0 = {vv0[0], vv0[1], vv0[2], vv0[3]};
      short4v va1 = {vv0[4], vv0[5], vv0[6], vv0[7]};
      short4v va2 = {vv1[0], vv1[1], vv1[2], vv1[3]};
      short4v va3 = {vv1[4], vv1[5], vv1[6], vv1[7]};
      acc[ni] = mfma16(va0, pk[0], acc[ni]);
      acc[ni] = mfma16(va1, pk[1], acc[ni]);
      acc[ni] = mfma16(va2, pk[2], acc[ni]);
      acc[ni] = mfma16(va3, pk[3], acc[ni]);
    }
    __builtin_amdgcn_s_setprio(0);

    if (it == TA){   // A-side complete within this unit's range
      if (SPLIT) emitP(0);
      else       writeout(TA, q0A);
#pragma unroll
      for (int ni = 0; ni < 4; ++ni) acc[ni] = f32x4{0.f, 0.f, 0.f, 0.f};
      rsum = 0.f;
    }
    if (it + 1 < hi){
#pragma unroll
      for (int t = 0; t < 4; ++t) relc[t] = reln[t];
    }
    __syncthreads();
  }
#undef STAGE

  if (SPLIT){
    if (TA >= hi)           emitP(0);   // unit entirely A (boundary beyond range)
    else if (TA != hi - 1)  emitP(1);   // unit ends in B (if TA==hi-1, A emitted at boundary, no B here)
  } else {
    writeout(TB, q0B);
  }
}

// ---------------- combine partials (3-way split) + suffix + normalize + store ----------------
__global__ __launch_bounds__(256) void attn_fin2_k(const u16* __restrict__ pa,
                                                   const float* __restrict__ pr,
                                                   const float* __restrict__ vsuf,
                                                   u16* __restrict__ ab){
  const int qt = blockIdx.x, bh = blockIdx.y;
  const int b = bh >> 4, h = bh & 15;
  const bool isB = qt >= 16;
  const int p = isB ? 31 - qt : qt;
  const int u0 = isB ? (p + 1) / 11 : 0;
  const int u1 = isB ? 3 : (p / 11 + 1);
  const int t01 = isB ? 1 : 0;
  const int r = threadIdx.x >> 2, cg = threadIdx.x & 3;
  float av[16] = {};
  float rs = 0.f;
  for (int uu = u0; uu < u1; ++uu){
    const size_t slot = (((size_t)bh * 16 + p) * 3 + uu) * 2 + t01;
    const u16* sp = pa + slot * 4096 + (size_t)r * 64 + cg * 16;
    uint4 w0 = *(const uint4*)sp;
    uint4 w1 = *(const uint4*)(sp + 8);
    const u16* pw0 = (const u16*)&w0;
    const u16* pw1 = (const u16*)&w1;
#pragma unroll
    for (int j = 0; j < 8; ++j) av[j] += bf2f(pw0[j]);
#pragma unroll
    for (int j = 0; j < 8; ++j) av[8 + j] += bf2f(pw1[j]);
    rs += pr[slot * 64 + r];
  }
  float invZ = 1.f / (rs + (float)(2048 - (qt + 1) * 64));
  const float* sufp = vsuf + ((size_t)bh * 33 + qt + 1) * 64 + cg * 16;
  u16 o[16];
#pragma unroll
  for (int j = 0; j < 16; ++j) o[j] = f2bf((av[j] + sufp[j]) * invZ);
  u16* dst = ab + ((size_t)b * 2048 + qt * 64 + r) * 1024 + h * 64 + cg * 16;
  *(uint4*)dst = *(const uint4*)&o[0];
  *(uint4*)(dst + 8) = *(const uint4*)&o[8];
}

// ---------------- launch ----------------
extern "C" void kernel_launch(void* const* d_in, const int* in_sizes, int n_in,
                              void* d_out, int out_size, void* d_ws, size_t ws_size,
                              hipStream_t stream){
  const float* x       = (const float*)d_in[0];
  const float* Wqkv    = (const float*)d_in[1];
  const float* bqkv    = (const float*)d_in[2];
  const float* Wproj   = (const float*)d_in[3];
  const float* bproj   = (const float*)d_in[4];
  const float* rel_emb = (const float*)d_in[5];
  const int*   rel     = (const int*)d_in[6];
  float* out = (float*)d_out;

  char* ws = (char*)d_ws;
  u16* xb     = (u16*)(ws);                      // 0-8 MB (x bf16; later attn output)
  u16* wqkvT  = (u16*)(ws + (8ull  << 20));      // 8-14 MB
  u16* wprojT = (u16*)(ws + (14ull << 20));      // 14-16 MB
  u16* qb     = (u16*)(ws + (16ull << 20));      // 16-24 MB
  u16* kb     = (u16*)(ws + (24ull << 20));      // 24-32 MB
  u8*   rel8  = (u8*)(ws + (32ull << 20));       // 32-40 MB (exactly 8 MiB)
  u16* vtb    = (u16*)(ws + (40ull << 20));      // 40-48 MB (V transposed+permuted)
  float* vsuf = (float*)(ws + (48ull << 20));    // 48-48.3 MB
  u16* paccb  = (u16*)(ws + (49ull << 20));      // 49-73 MB (bf16 partials, 24 MB)
  float* prsum= (float*)(ws + (73ull << 20));    // 73-73.8 MB
  const bool useSplit = ws_size >= (74ull << 20);
  const bool useU8    = ws_size >= (41ull << 20);

  prep_k<<<useU8 ? 16384 : 8192, 256, 0, stream>>>(x, xb, Wqkv, wqkvT, Wproj, wprojT, rel, rel8);
  gemm_qkv_k<<<dim3(24, 32), 256, 0, stream>>>(xb, wqkvT, bqkv, qb, kb, vtb);
  vsuf2_k<<<32, 256, 0, stream>>>(vtb, vsuf);
  if (useSplit && useU8){
    attn_k<1, 1><<<dim3(1536), 256, 0, stream>>>(qb, kb, vtb, vsuf, rel8, rel_emb, xb, paccb, prsum);
    attn_fin2_k<<<dim3(32, 32), 256, 0, stream>>>(paccb, prsum, vsuf, xb);
  } else if (useU8){
    attn_k<1, 0><<<dim3(16, 32), 256, 0, stream>>>(qb, kb, vtb, vsuf, rel8, rel_emb, xb, paccb, prsum);
  } else {
    attn_k<0, 0><<<dim3(16, 32), 256, 0, stream>>>(qb, kb, vtb, vsuf, rel, rel_emb, xb, paccb, prsum);
  }
  gemm_bt_k<64><<<dim3(16, 32), 256, 0, stream>>>(xb, wprojT, bproj, out, 4096, 1024, 1024);
}

// Round 13
// 138.639 us; speedup vs baseline: 1.0246x; 1.0190x over previous
//
#include <hip/hip_runtime.h>

typedef unsigned short u16;
typedef unsigned char u8;
typedef __attribute__((ext_vector_type(8))) short short8;
typedef __attribute__((ext_vector_type(4))) short short4v;
typedef __attribute__((ext_vector_type(4))) float f32x4;

#define GLD16(g, l) __builtin_amdgcn_global_load_lds( \
    (const __attribute__((address_space(1))) void*)(g), \
    (__attribute__((address_space(3))) void*)(l), 16, 0, 0)

__device__ __forceinline__ float bf2f(u16 u){
  union { unsigned int i; float f; } v; v.i = ((unsigned int)u) << 16; return v.f;
}
__device__ __forceinline__ u16 f2bf(float f){
  union { float f; unsigned int i; } v; v.f = f;
  unsigned int u = v.i;
  unsigned int r = (u + 0x7FFFu + ((u >> 16) & 1u)) >> 16;
  return (u16)r;
}

__device__ __forceinline__ f32x4 mfma16(short4v a, short4v b, f32x4 c){
#if __has_builtin(__builtin_amdgcn_mfma_f32_16x16x16bf16_1k)
  return __builtin_amdgcn_mfma_f32_16x16x16bf16_1k(a, b, c, 0, 0, 0);
#else
  asm volatile("s_nop 1\n\tv_mfma_f32_16x16x16_bf16 %0, %1, %2, %0" : "+v"(c) : "v"(a), "v"(b));
  return c;
#endif
}

// ---------------- fused prep: x->bf16 | Wqkv^T | Wproj^T | rel->u8 ----------------
__global__ __launch_bounds__(256) void prep_k(const float* __restrict__ x, u16* __restrict__ xb,
                                              const float* __restrict__ Wqkv, u16* __restrict__ wqkvT,
                                              const float* __restrict__ Wproj, u16* __restrict__ wprojT,
                                              const int* __restrict__ rel, u8* __restrict__ rel8){
  const int bid = blockIdx.x, t = threadIdx.x;
  if (bid < 4096){
    int i = bid * 256 + t;
    float4 v = ((const float4*)x)[i];
    unsigned long long pk = (unsigned long long)f2bf(v.x)
      | ((unsigned long long)f2bf(v.y) << 16)
      | ((unsigned long long)f2bf(v.z) << 32)
      | ((unsigned long long)f2bf(v.w) << 48);
    ((unsigned long long*)xb)[i] = pk;
  } else if (bid < 8192){
    const float* W; u16* Wt; int K, N, blk, nbx;
    if (bid < 7168){ W = Wqkv; Wt = wqkvT; K = 1024; N = 3072; blk = bid - 4096; nbx = 96; }
    else           { W = Wproj; Wt = wprojT; K = 1024; N = 1024; blk = bid - 7168; nbx = 32; }
    __shared__ float tl[32][33];
    int n0 = (blk % nbx) * 32, k0 = (blk / nbx) * 32;
    int tx = t & 31, ty = t >> 5;
    for (int i = ty; i < 32; i += 8)
      tl[i][tx] = W[(size_t)(k0 + i) * N + n0 + tx];
    __syncthreads();
    for (int i = ty; i < 32; i += 8)
      Wt[(size_t)(n0 + i) * K + k0 + tx] = f2bf(tl[tx][i]);
  } else {
    int i = (bid - 8192) * 256 + t;
    int4 v = ((const int4*)rel)[i];
    unsigned int pk = (unsigned int)(v.x & 255) | ((unsigned int)(v.y & 255) << 8)
      | ((unsigned int)(v.z & 255) << 16) | ((unsigned int)(v.w & 255) << 24);
    ((unsigned int*)rel8)[i] = pk;
  }
}

// ---------------- QKV GEMM: 128x128 tile, BK=32, 3-buffer counted-vmcnt pipeline ----------------
__global__ __launch_bounds__(256) void gemm_qkv_k(const u16* __restrict__ A, const u16* __restrict__ Bt,
                                                  const float* __restrict__ bias,
                                                  u16* __restrict__ oq, u16* __restrict__ okk, u16* __restrict__ vt){
  __shared__ u16 la[3][128 * 32];   // 3 x 8 KB
  __shared__ u16 lb[3][128 * 32];   // 3 x 8 KB
  const int K = 1024;
  const int t = threadIdx.x, w = t >> 6, lane = t & 63;
  const int l15 = lane & 15, l4 = lane >> 4;
  const int m0 = blockIdx.y * 128, n0 = blockIdx.x * 128;
  const int wr = w >> 1, wc = w & 1;
  f32x4 acc[4][4] = {};
  const u16* Abase = A + (size_t)m0 * K;
  const u16* Bbase = Bt + (size_t)n0 * K;

  const int srow0 = t >> 2, srow1 = 64 + (t >> 2);
  const int cg = t & 3;
  const int sc0 = cg ^ (srow0 & 3), sc1 = cg ^ (srow1 & 3);
  const int wbase0 = (w * 64) * 8, wbase1 = (256 + w * 64) * 8;

#define QSTAGE(kt, buf) do {                                                        \
    GLD16(Abase + (size_t)srow0 * K + (kt) * 32 + sc0 * 8, &la[buf][wbase0]);       \
    GLD16(Abase + (size_t)srow1 * K + (kt) * 32 + sc1 * 8, &la[buf][wbase1]);       \
    GLD16(Bbase + (size_t)srow0 * K + (kt) * 32 + sc0 * 8, &lb[buf][wbase0]);       \
    GLD16(Bbase + (size_t)srow1 * K + (kt) * 32 + sc1 * 8, &lb[buf][wbase1]);       \
  } while (0)

  QSTAGE(0, 0);
  QSTAGE(1, 1);
  for (int ki = 0; ki < 32; ++ki){
    __builtin_amdgcn_sched_barrier(0);
    if (ki < 31) asm volatile("s_waitcnt vmcnt(4)" ::: "memory");
    else         asm volatile("s_waitcnt vmcnt(0)" ::: "memory");
    __builtin_amdgcn_s_barrier();
    __builtin_amdgcn_sched_barrier(0);
    if (ki + 2 < 32) QSTAGE(ki + 2, (ki + 2) % 3);
    const int cb = ki % 3;
    short8 af[4], bfr[4];
#pragma unroll
    for (int mi = 0; mi < 4; ++mi){
      int row = wr * 64 + mi * 16 + l15;
      af[mi] = *(const short8*)&la[cb][row * 32 + ((l4 ^ (row & 3)) * 8)];
    }
#pragma unroll
    for (int ni = 0; ni < 4; ++ni){
      int row = wc * 64 + ni * 16 + l15;
      bfr[ni] = *(const short8*)&lb[cb][row * 32 + ((l4 ^ (row & 3)) * 8)];
    }
    __builtin_amdgcn_s_setprio(1);
#pragma unroll
    for (int mi = 0; mi < 4; ++mi)
#pragma unroll
      for (int ni = 0; ni < 4; ++ni)
        acc[mi][ni] = __builtin_amdgcn_mfma_f32_16x16x32_bf16(af[mi], bfr[ni], acc[mi][ni], 0, 0, 0);
    __builtin_amdgcn_s_setprio(0);
  }
#undef QSTAGE

#pragma unroll
  for (int mi = 0; mi < 4; ++mi){
    const int m_base = m0 + wr * 64 + mi * 16 + l4 * 4;
    const int bsel = m_base >> 11, s0q = m_base & 2047;
#pragma unroll
    for (int ni = 0; ni < 4; ++ni){
      int n = n0 + wc * 64 + ni * 16 + l15;
      float vb = bias[n];
      int tt = n >> 10, rr = n & 1023, head = rr >> 6, dd = rr & 63;
      if (tt == 2){
        int c = s0q >> 6, w6 = s0q & 63;
        int pj0 = (((w6 >> 2) & 3) << 4) | (((w6 >> 4) & 3) << 2);
        u16 o4[4];
#pragma unroll
        for (int r = 0; r < 4; ++r) o4[r] = f2bf(acc[mi][ni][r] + vb);
        *(uint2*)(vt + ((size_t)(bsel * 16 + head) * 64 + dd) * 2048 + c * 64 + pj0) = *(const uint2*)o4;
      } else {
        u16* dst = (tt == 0) ? oq : okk;
#pragma unroll
        for (int r = 0; r < 4; ++r)
          dst[(((size_t)(bsel * 16 + head)) * 2048 + s0q + r) * 64 + dd] = f2bf(acc[mi][ni][r] + vb);
      }
    }
  }
}

// ---------------- proj GEMM (B^T input), BK=64, XOR-swizzled LDS, fp32 out ----------------
template<int BN>
__global__ __launch_bounds__(256) void gemm_bt_k(const u16* __restrict__ A, const u16* __restrict__ Bt,
                                                 const float* __restrict__ bias, float* __restrict__ of,
                                                 int M, int N, int K){
  __shared__ u16 la[128 * 64];
  __shared__ u16 lb[BN * 64];
  const int t = threadIdx.x, w = t >> 6, lane = t & 63;
  const int l15 = lane & 15, l4 = lane >> 4;
  const int m0 = blockIdx.y * 128, n0 = blockIdx.x * BN;
  const int wr = w >> 1, wc = w & 1;
  constexpr int NI = BN / 32;
  f32x4 acc[4][NI] = {};
  const u16* Abase = A + (size_t)m0 * K;
  const u16* Bbase = Bt + (size_t)n0 * K;
  for (int kt = 0; kt < K; kt += 64){
    __syncthreads();
#pragma unroll
    for (int i = 0; i < 4; ++i){
      int chunk = i * 256 + t;
      int row = chunk >> 3, cs = chunk & 7;
      int c = cs ^ (row & 7);
      GLD16(Abase + (size_t)row * K + kt + c * 8, &la[(i * 256 + w * 64) * 8]);
    }
#pragma unroll
    for (int i = 0; i < BN / 32; ++i){
      int chunk = i * 256 + t;
      int row = chunk >> 3, cs = chunk & 7;
      int c = cs ^ (row & 7);
      GLD16(Bbase + (size_t)row * K + kt + c * 8, &lb[(i * 256 + w * 64) * 8]);
    }
    asm volatile("s_waitcnt vmcnt(0)" ::: "memory");
    __syncthreads();
    short8 af[4][2], bfr[NI][2];
#pragma unroll
    for (int mi = 0; mi < 4; ++mi){
      int row = wr * 64 + mi * 16 + l15;
#pragma unroll
      for (int h = 0; h < 2; ++h)
        af[mi][h] = *(const short8*)&la[row * 64 + (((h * 4 + l4) ^ (row & 7)) * 8)];
    }
#pragma unroll
    for (int ni = 0; ni < NI; ++ni){
      int row = wc * (BN / 2) + ni * 16 + l15;
#pragma unroll
      for (int h = 0; h < 2; ++h)
        bfr[ni][h] = *(const short8*)&lb[row * 64 + (((h * 4 + l4) ^ (row & 7)) * 8)];
    }
#pragma unroll
    for (int mi = 0; mi < 4; ++mi)
#pragma unroll
      for (int ni = 0; ni < NI; ++ni){
        acc[mi][ni] = __builtin_amdgcn_mfma_f32_16x16x32_bf16(af[mi][0], bfr[ni][0], acc[mi][ni], 0, 0, 0);
        acc[mi][ni] = __builtin_amdgcn_mfma_f32_16x16x32_bf16(af[mi][1], bfr[ni][1], acc[mi][ni], 0, 0, 0);
      }
  }
#pragma unroll
  for (int mi = 0; mi < 4; ++mi){
#pragma unroll
    for (int ni = 0; ni < NI; ++ni){
#pragma unroll
      for (int r = 0; r < 4; ++r){
        int m = m0 + wr * 64 + mi * 16 + l4 * 4 + r;
        int n = n0 + wc * (BN / 2) + ni * 16 + l15;
        of[(size_t)m * N + n] = acc[mi][ni][r] + bias[n];
      }
    }
  }
}

// ---------------- V chunk sums from vt (perm-invariant) + suffix scan ----------------
__global__ __launch_bounds__(256) void vsuf2_k(const u16* __restrict__ vt, float* __restrict__ vsuf){
  __shared__ float part[32][64];
  const int bh = blockIdx.x;
  const int d = threadIdx.x & 63, qtr = threadIdx.x >> 6;
  const u16* row = vt + ((size_t)bh * 64 + d) * 2048;
  for (int c = qtr * 8; c < qtr * 8 + 8; ++c){
    float s = 0.f;
#pragma unroll
    for (int jv = 0; jv < 8; ++jv){
      short8 v = *(const short8*)(row + c * 64 + jv * 8);
#pragma unroll
      for (int e = 0; e < 8; ++e) s += bf2f((u16)v[e]);
    }
    part[c][d] = s;
  }
  __syncthreads();
  if (threadIdx.x < 64){
    float run = 0.f;
    vsuf[((size_t)bh * 33 + 32) * 64 + d] = 0.f;
    for (int c = 31; c >= 0; --c){
      run += part[c][d];
      vsuf[((size_t)bh * 33 + c) * 64 + d] = run;
    }
  }
}

// ---------------- fused rel-bias causal attention (swapped-operand, cross-block split) ----------------
// Counted-vmcnt single-barrier loop: per iter [vmcnt(4); s_barrier; STAGE(i+1)+relload; compute(i)].
// Hazards: STAGE(i+1) overwrites buf read at compute(i-1), done before barrier(i); compute(i)'s
// buf staged at iter i-1, completion = vmcnt(4) (4 newest = rel loads) + barrier. No ds_writes.
template<int U8, int SPLIT>
__global__ __launch_bounds__(256, 4) void attn_k(const u16* __restrict__ qb, const u16* __restrict__ kb,
                                                 const u16* __restrict__ vt, const float* __restrict__ vsuf,
                                                 const void* __restrict__ relp, const float* __restrict__ rel_emb,
                                                 u16* __restrict__ ab, float* __restrict__ pacc,
                                                 float* __restrict__ prsum){
  __shared__ u16 Kt[2][64 * 64];
  __shared__ u16 Vt[2][64 * 64];
  __shared__ float remb[64];
  int p, hf, bh;
  if (SPLIT){
    const int lid = blockIdx.x;
    const int bhgrp = lid & 7, within = (lid >> 3) & 3, pf = lid >> 5;
    bh = bhgrp * 4 + within;
    p = pf >> 1; hf = pf & 1;
  } else {
    p = blockIdx.x; hf = 0; bh = blockIdx.y;
  }
  const int b = bh >> 4, h = bh & 15;
  const int TA = p, TB = 31 - p;
  const int q0A = TA * 64, q0B = TB * 64;
  const int tid = threadIdx.x, w = tid >> 6, lane = tid & 63;
  const int l15 = lane & 15, l4 = lane >> 4;
  if (tid < 64) remb[tid] = rel_emb[tid * 16 + h] * (0.125f * 1.44269504088896f);
  const u16* kbh = kb + ((size_t)bh * 2048) * 64;
  const u16* vbh = vt + ((size_t)bh * 64) * 2048;
  const u16* qA = qb + (((size_t)bh * 2048) + q0A + w * 16 + l15) * 64 + l4 * 8;
  const u16* qB = qb + (((size_t)bh * 2048) + q0B + w * 16 + l15) * 64 + l4 * 8;
  const short8 aqA0 = *(const short8*)qA, aqA1 = *(const short8*)(qA + 32);
  const short8 aqB0 = *(const short8*)qB, aqB1 = *(const short8*)(qB + 32);
  const u8*  r8A  = (const u8*)relp + ((size_t)b * 2048 + q0A + w * 16 + l15) * 2048;
  const u8*  r8B  = (const u8*)relp + ((size_t)b * 2048 + q0B + w * 16 + l15) * 2048;
  const int* r32A = (const int*)relp + ((size_t)b * 2048 + q0A + w * 16 + l15) * 2048;
  const int* r32B = (const int*)relp + ((size_t)b * 2048 + q0B + w * 16 + l15) * 2048;

  const int srow0 = (tid >> 3), srow1 = 32 + (tid >> 3);
  const int scs = tid & 7;
  const int sc0 = scs ^ (srow0 & 7), sc1 = scs ^ (srow1 & 7);
  const int sldsoff = (w * 64) * 8;

#define STAGE(ktile, buf) do {                                                       \
    GLD16(kbh + (size_t)((ktile) * 64 + srow0) * 64 + sc0 * 8, &Kt[buf][sldsoff]);   \
    GLD16(kbh + (size_t)((ktile) * 64 + srow1) * 64 + sc1 * 8, &Kt[buf][2048 + sldsoff]); \
    GLD16(vbh + (size_t)srow0 * 2048 + (ktile) * 64 + sc0 * 8, &Vt[buf][sldsoff]);   \
    GLD16(vbh + (size_t)srow1 * 2048 + (ktile) * 64 + sc1 * 8, &Vt[buf][2048 + sldsoff]); \
  } while (0)

  f32x4 acc[4] = {};
  float rsum = 0.f;
  unsigned int relc[4], reln[4];

  auto relload = [&](bool isA, int kt, unsigned int* dst){
    int off = kt * 64 + 4 * l4;
    if (U8){
      const u8* pp = isA ? r8A : r8B;
#pragma unroll
      for (int t = 0; t < 4; ++t) dst[t] = *(const unsigned int*)(pp + off + 16 * t);
    } else {
      const int* pp = isA ? r32A : r32B;
#pragma unroll
      for (int t = 0; t < 4; ++t){
        int4 v4 = *(const int4*)(pp + off + 16 * t);
        dst[t] = (unsigned int)(v4.x & 255) | ((unsigned int)(v4.y & 255) << 8)
               | ((unsigned int)(v4.z & 255) << 16) | ((unsigned int)(v4.w & 255) << 24);
      }
    }
  };

  auto writeout = [&](int Td, int q0){
    asm volatile("s_nop 7\n\ts_nop 7" :::);
    float s = rsum;
    s += __shfl_xor(s, 16);
    s += __shfl_xor(s, 32);
    float invZ = 1.f / (s + (float)(2048 - (Td + 1) * 64));
    int qg = q0 + w * 16 + l15;
    const float* sufp = vsuf + ((size_t)bh * 33 + Td + 1) * 64;
#pragma unroll
    for (int ni = 0; ni < 4; ++ni){
      float4 sv = *(const float4*)(sufp + ni * 16 + 4 * l4);
      unsigned int lo2 = (unsigned int)f2bf((acc[ni][0] + sv.x) * invZ)
                       | ((unsigned int)f2bf((acc[ni][1] + sv.y) * invZ) << 16);
      unsigned int hi2 = (unsigned int)f2bf((acc[ni][2] + sv.z) * invZ)
                       | ((unsigned int)f2bf((acc[ni][3] + sv.w) * invZ) << 16);
      uint2 o; o.x = lo2; o.y = hi2;
      *(uint2*)(ab + ((size_t)b * 2048 + qg) * 1024 + h * 64 + ni * 16 + 4 * l4) = o;
    }
  };

  const int lo = (SPLIT && hf) ? 17 : 0;
  const int hi = (SPLIT && !hf) ? 17 : 33;

  {
    bool isA0 = (lo <= TA);
    int kt0 = isA0 ? lo : lo - TA - 1;
    STAGE(kt0, 0);
    relload(isA0, kt0, relc);
  }

  for (int it = lo; it < hi; ++it){
    const bool isA = (it <= TA);
    const int kt = isA ? it : (it - TA - 1);
    const int cur = (it - lo) & 1;

    // counted wait: 4 newest outstanding = this iter's rel loads; everything
    // older (incl. all waves' STAGE(it) after the barrier) is complete.
    __builtin_amdgcn_sched_barrier(0);
    asm volatile("s_waitcnt vmcnt(4)" ::: "memory");
    __builtin_amdgcn_s_barrier();
    __builtin_amdgcn_sched_barrier(0);

    if (it + 1 < hi){
      const bool nA = (it + 1 <= TA);
      const int nkt = nA ? (it + 1) : (it - TA);
      STAGE(nkt, cur ^ 1);
      relload(nA, nkt, reln);
    }

    const short8 a0 = isA ? aqA0 : aqB0;
    const short8 a1 = isA ? aqA1 : aqB1;
    const bool diag = (kt == (isA ? TA : TB));

    short4v pk[4];
    __builtin_amdgcn_s_setprio(1);
#pragma unroll
    for (int t = 0; t < 4; ++t){
      const int krow = 16 * t + l15;
      const u16* kbase = &Kt[cur][krow * 64];
      short8 bk0 = *(const short8*)&kbase[((l4)     ^ (krow & 7)) * 8];
      short8 bk1 = *(const short8*)&kbase[((4 + l4) ^ (krow & 7)) * 8];
      f32x4 sf = {0.f, 0.f, 0.f, 0.f};
      sf = __builtin_amdgcn_mfma_f32_16x16x32_bf16(bk0, a0, sf, 0, 0, 0);
      sf = __builtin_amdgcn_mfma_f32_16x16x32_bf16(bk1, a1, sf, 0, 0, 0);
      unsigned int rw = relc[t];
      const int kk = 16 * t + 4 * l4;
      float prv[4];
#pragma unroll
      for (int r = 0; r < 4; ++r){
        float sc = sf[r] * remb[(rw >> (8 * r)) & 255];
        if (diag) sc = (kk + r <= w * 16 + l15) ? sc : 0.f;
        float pv = __builtin_amdgcn_exp2f(sc);
        rsum += pv;
        prv[r] = pv;
      }
      union { unsigned int u[2]; short4v s; } pu;
      asm("v_cvt_pk_bf16_f32 %0, %1, %2" : "=v"(pu.u[0]) : "v"(prv[0]), "v"(prv[1]));
      asm("v_cvt_pk_bf16_f32 %0, %1, %2" : "=v"(pu.u[1]) : "v"(prv[2]), "v"(prv[3]));
      pk[t] = pu.s;
    }
    asm volatile("s_nop 2" :::);
#pragma unroll
    for (int ni = 0; ni < 4; ++ni){
      const int drow = ni * 16 + l15;
      const u16* vbase = &Vt[cur][drow * 64];
      short8 vv0 = *(const short8*)&vbase[(((2 * l4)     ^ (drow & 7))) * 8];
      short8 vv1 = *(const short8*)&vbase[(((2 * l4 + 1) ^ (drow & 7))) * 8];
      short4v va0 = {vv0[0], vv0[1], vv0[2], vv0[3]};
      short4v va1 = {vv0[4], vv0[5], vv0[6], vv0[7]};
      short4v va2 = {vv1[0], vv1[1], vv1[2], vv1[3]};
      short4v va3 = {vv1[4], vv1[5], vv1[6], vv1[7]};
      acc[ni] = mfma16(va0, pk[0], acc[ni]);
      acc[ni] = mfma16(va1, pk[1], acc[ni]);
      acc[ni] = mfma16(va2, pk[2], acc[ni]);
      acc[ni] = mfma16(va3, pk[3], acc[ni]);
    }
    __builtin_amdgcn_s_setprio(0);

    if (it == TA){   // A complete (only reachable when hf==0)
      writeout(TA, q0A);
#pragma unroll
      for (int ni = 0; ni < 4; ++ni) acc[ni] = f32x4{0.f, 0.f, 0.f, 0.f};
      rsum = 0.f;
    }
    if (it + 1 < hi){
#pragma unroll
      for (int t = 0; t < 4; ++t) relc[t] = reln[t];
    }
  }
#undef STAGE

  if (SPLIT){
    asm volatile("s_nop 7\n\ts_nop 7" :::);
    float s = rsum;
    s += __shfl_xor(s, 16);
    s += __shfl_xor(s, 32);
    const size_t slot = (((size_t)bh * 16 + p) * 2 + hf);
    float* pslot = pacc + slot * 4096;
#pragma unroll
    for (int ni = 0; ni < 4; ++ni)
      *(f32x4*)(pslot + (w * 16 + l15) * 64 + ni * 16 + 4 * l4) = acc[ni];
    if (l4 == 0) prsum[slot * 64 + w * 16 + l15] = s;
  } else {
    writeout(TB, q0B);
  }
}

// ---------------- combine B partials + suffix + normalize + store ----------------
__global__ __launch_bounds__(256) void attn_fin_k(const float* __restrict__ pacc,
                                                  const float* __restrict__ prsum,
                                                  const float* __restrict__ vsuf,
                                                  u16* __restrict__ ab){
  const int p = blockIdx.x, bh = blockIdx.y;
  const int b = bh >> 4, h = bh & 15;
  const int TB = 31 - p, q0 = TB * 64;
  const int r = threadIdx.x >> 2, cg = threadIdx.x & 3;
  const size_t slot = ((size_t)bh * 16 + p) * 2;
  const size_t base = slot * 4096 + r * 64 + cg * 16;
  float rs = prsum[slot * 64 + r] + prsum[(slot + 1) * 64 + r];
  float invZ = 1.f / (rs + (float)(2048 - (TB + 1) * 64));
  const float* sufp = vsuf + ((size_t)bh * 33 + TB + 1) * 64 + cg * 16;
  u16 o[16];
#pragma unroll
  for (int j = 0; j < 4; ++j){
    f32x4 a0 = *(const f32x4*)(pacc + base + j * 4);
    f32x4 a1 = *(const f32x4*)(pacc + base + 4096 + j * 4);
    f32x4 sv = *(const f32x4*)(sufp + j * 4);
#pragma unroll
    for (int e = 0; e < 4; ++e) o[j * 4 + e] = f2bf((a0[e] + a1[e] + sv[e]) * invZ);
  }
  u16* dst = ab + ((size_t)b * 2048 + q0 + r) * 1024 + h * 64 + cg * 16;
  *(uint4*)dst = *(const uint4*)&o[0];
  *(uint4*)(dst + 8) = *(const uint4*)&o[8];
}

// ---------------- launch ----------------
extern "C" void kernel_launch(void* const* d_in, const int* in_sizes, int n_in,
                              void* d_out, int out_size, void* d_ws, size_t ws_size,
                              hipStream_t stream){
  const float* x       = (const float*)d_in[0];
  const float* Wqkv    = (const float*)d_in[1];
  const float* bqkv    = (const float*)d_in[2];
  const float* Wproj   = (const float*)d_in[3];
  const float* bproj   = (const float*)d_in[4];
  const float* rel_emb = (const float*)d_in[5];
  const int*   rel     = (const int*)d_in[6];
  float* out = (float*)d_out;

  char* ws = (char*)d_ws;
  u16* xb     = (u16*)(ws);                      // 0-8 MB (x bf16; later attn output)
  u16* wqkvT  = (u16*)(ws + (8ull  << 20));      // 8-14 MB
  u16* wprojT = (u16*)(ws + (14ull << 20));      // 14-16 MB
  u16* qb     = (u16*)(ws + (16ull << 20));      // 16-24 MB
  u16* kb     = (u16*)(ws + (24ull << 20));      // 24-32 MB
  u16* vtb    = (u16*)(ws + (40ull << 20));      // 40-48 MB (V transposed+permuted)
  float* vsuf = (float*)(ws + (48ull << 20));                   // 270 KB
  float* pacc = (float*)(ws + (49ull << 20));    // 49-65 MB (B partials f32)
  float* prsum= (float*)(ws + (65ull << 20) + (512ull << 10));  // 256 KB
  u8*   rel8  = (u8*)(ws + (66ull << 20));       // 66-74.4 MB
  const bool useSplit = ws_size >= (67ull << 20);
  const bool useU8    = ws_size >= (75ull << 20);

  prep_k<<<useU8 ? 16384 : 8192, 256, 0, stream>>>(x, xb, Wqkv, wqkvT, Wproj, wprojT, rel, rel8);
  gemm_qkv_k<<<dim3(24, 32), 256, 0, stream>>>(xb, wqkvT, bqkv, qb, kb, vtb);
  vsuf2_k<<<32, 256, 0, stream>>>(vtb, vsuf);
  if (useU8)
    attn_k<1, 1><<<dim3(1024), 256, 0, stream>>>(qb, kb, vtb, vsuf, rel8, rel_emb, xb, pacc, prsum);
  else if (useSplit)
    attn_k<0, 1><<<dim3(1024), 256, 0, stream>>>(qb, kb, vtb, vsuf, rel, rel_emb, xb, pacc, prsum);
  else
    attn_k<0, 0><<<dim3(16, 32), 256, 0, stream>>>(qb, kb, vtb, vsuf, rel, rel_emb, xb, pacc, prsum);
  if (useSplit || useU8)
    attn_fin_k<<<dim3(16, 32), 256, 0, stream>>>(pacc, prsum, vsuf, xb);
  gemm_bt_k<64><<<dim3(16, 32), 256, 0, stream>>>(xb, wprojT, bproj, out, 4096, 1024, 1024);
}